// Round 4
// baseline (313.069 us; speedup 1.0000x reference)
//
#include <hip/hip_runtime.h>
#include <hip/hip_cooperative_groups.h>
#include <stdint.h>

namespace cg = cooperative_groups;

// ---------------------------------------------------------------------------
// BNNLinear: out = BatchNorm( sign(x) @ sign(W)^T )
//   x: [M, K] f32, W: [N, K] f32, gamma/beta: [N] f32  ->  out: [M, N] f32
//
// Round 4: ONE cooperative kernel, grid = 512 blocks (fits 768-block
// co-residency budget at ~144 combined regs; round 3's 1024 did not -> launch
// validation failed -> silent zeros). Each block owns TWO 128x128 tiles:
//   phase 0: zero stats + binarize x,W -> i8 (grid-stride)
//   grid.sync()
//   phase 1: tile0 GEMM -> stats atomics + raw C store;
//            tile1 GEMM -> stats atomics, acc kept in registers
//   grid.sync()
//   phase 2: tile1 normalized from registers; tile0 re-read (block-local,
//            L2-hot) and normalized with coalesced float4
// Host checks the cooperative launch return code and falls back to the
// round-2 style multi-kernel pipeline if validation fails.
// ---------------------------------------------------------------------------

typedef int int32x4 __attribute__((ext_vector_type(4)));

#define BM 128
#define BN 128
#define BKI 64
#define EPS_BN 1e-5f

__device__ __forceinline__ void load16_lds(const void* g, void* l) {
  // 16B per lane, LDS dest = wave-uniform base + lane*16
  __builtin_amdgcn_global_load_lds(
      (const __attribute__((address_space(1))) void*)g,
      (__attribute__((address_space(3))) void*)l,
      16, 0, 0);
}

__device__ __forceinline__ char sgn(float v) {
  return v > 0.f ? (char)1 : (v < 0.f ? (char)-1 : (char)0);
}

// ---- shared tile GEMM core (i8, exact): acc += A_tile * B_tile^T ----------
__device__ __forceinline__ void gemm_tile(
    const char* __restrict__ Abin, const char* __restrict__ Bbin,
    int rowBlock, int colBlock, int K, char* sA, char* sB,
    int wave, int lane, int32x4 acc[4][4]) {
  const int laneRow   = lane >> 2;        // 0..15
  const int laneChunk = (lane & 3) * 16;  // byte offset within 64B row

  const char* Ag = Abin + (size_t)(rowBlock + wave * 32 + laneRow) * K + laneChunk;
  const char* Bg = Bbin + (size_t)(colBlock + wave * 32 + laneRow) * K + laneChunk;
  char* sAw = &sA[(wave * 32) * BKI];
  char* sBw = &sB[(wave * 32) * BKI];

  const int f    = lane & 15;
  const int quad = lane >> 4;
  const int wr = (wave >> 1) * 64;
  const int wc = (wave & 1) * 64;

  for (int k0 = 0; k0 < K; k0 += BKI) {
    __syncthreads();  // prior ds_reads complete before overwrite
    load16_lds(Ag + k0,                  sAw);
    load16_lds(Ag + k0 + 16 * (size_t)K, sAw + 16 * BKI);
    load16_lds(Bg + k0,                  sBw);
    load16_lds(Bg + k0 + 16 * (size_t)K, sBw + 16 * BKI);
    __syncthreads();  // vmcnt drain -> staging visible

    int32x4 af[4], bfr[4];
#pragma unroll
    for (int mi = 0; mi < 4; ++mi)
      af[mi] = *reinterpret_cast<const int32x4*>(
          &sA[(wr + mi * 16 + f) * BKI + quad * 16]);
#pragma unroll
    for (int ni = 0; ni < 4; ++ni)
      bfr[ni] = *reinterpret_cast<const int32x4*>(
          &sB[(wc + ni * 16 + f) * BKI + quad * 16]);
#pragma unroll
    for (int mi = 0; mi < 4; ++mi)
#pragma unroll
      for (int ni = 0; ni < 4; ++ni)
        acc[mi][ni] = __builtin_amdgcn_mfma_i32_16x16x64_i8(
            af[mi], bfr[ni], acc[mi][ni], 0, 0, 0);
  }
}

// per-column sum/sumsq atomics (+ optional raw C store)
// C/D layout: col = lane&15, row = quad*4 + reg (dtype-independent, verified)
__device__ __forceinline__ void tile_stats(
    const int32x4 acc[4][4], float* __restrict__ colSum,
    float* __restrict__ colSq, float* __restrict__ Craw, int N,
    int rowBlock, int colBlock, int wave, int lane, bool storeRaw) {
  const int f    = lane & 15;
  const int quad = lane >> 4;
  const int wr = (wave >> 1) * 64;
  const int wc = (wave & 1) * 64;
#pragma unroll
  for (int ni = 0; ni < 4; ++ni) {
    const int col = colBlock + wc + ni * 16 + f;
    float s = 0.f, sq = 0.f;
#pragma unroll
    for (int mi = 0; mi < 4; ++mi) {
      const int row0 = rowBlock + wr + mi * 16 + quad * 4;
      float* Cp = Craw + (size_t)row0 * N + col;
#pragma unroll
      for (int r = 0; r < 4; ++r) {
        float v = (float)acc[mi][ni][r];
        if (storeRaw) Cp[(size_t)r * N] = v;
        s += v;
        sq += v * v;
      }
    }
    s  += __shfl_xor(s, 16);  s  += __shfl_xor(s, 32);
    sq += __shfl_xor(sq, 16); sq += __shfl_xor(sq, 32);
    if (quad == 0) {
      atomicAdd(&colSum[col], s);   // integer-valued: exact in fp32
      atomicAdd(&colSq[col], sq);
    }
  }
}

// ---- the fused cooperative kernel -----------------------------------------
__global__ __launch_bounds__(256, 2) void bnn_fused_kernel(
    const float* __restrict__ x, const float* __restrict__ w,
    const float* __restrict__ gamma, const float* __restrict__ beta,
    char* __restrict__ Abin, char* __restrict__ Bbin,
    float* __restrict__ colSum, float* __restrict__ colSq,
    float* __restrict__ C, int M, int N, int K) {
  cg::grid_group grid = cg::this_grid();

  const int tid  = threadIdx.x;
  const int gtid = blockIdx.x * blockDim.x + tid;
  const int gstride = gridDim.x * blockDim.x;

  // ---- phase 0: zero stats + binarize ------------------------------------
  if (gtid < 2 * N) colSum[gtid] = 0.f;  // colSum|colSq contiguous
  {
    const int nx4 = (M * K) / 4;
    const int ntot = nx4 + (N * K) / 4;
    for (int idx = gtid; idx < ntot; idx += gstride) {
      const float4* src;
      char* dst;
      int i;
      if (idx < nx4) {
        src = reinterpret_cast<const float4*>(x); dst = Abin; i = idx;
      } else {
        src = reinterpret_cast<const float4*>(w); dst = Bbin; i = idx - nx4;
      }
      float4 v = src[i];
      char4 o;
      o.x = sgn(v.x); o.y = sgn(v.y); o.z = sgn(v.z); o.w = sgn(v.w);
      reinterpret_cast<char4*>(dst)[i] = o;
    }
  }

  grid.sync();  // binarized data + zeroed stats visible device-wide

  // ---- phase 1: two tiles per block --------------------------------------
  __shared__ __align__(16) char sA[BM * BKI];  // 8 KiB
  __shared__ __align__(16) char sB[BN * BKI];  // 8 KiB

  const int wave = tid >> 6;
  const int lane = tid & 63;
  const int nby = M / BM;  // 64: consecutive tile-ids share bx (B-panel in L2)

  const int t0 = blockIdx.x;
  const int t1 = blockIdx.x + gridDim.x;
  const int row0 = (t0 % nby) * BM, col0 = (t0 / nby) * BN;
  const int row1 = (t1 % nby) * BM, col1 = (t1 / nby) * BN;

  int32x4 acc[4][4];

  // tile 0: stats + raw C store (re-read by this same block in phase 2)
#pragma unroll
  for (int mi = 0; mi < 4; ++mi)
#pragma unroll
    for (int ni = 0; ni < 4; ++ni) acc[mi][ni] = int32x4{0, 0, 0, 0};
  gemm_tile(Abin, Bbin, row0, col0, K, sA, sB, wave, lane, acc);
  tile_stats(acc, colSum, colSq, C, N, row0, col0, wave, lane, true);

  // tile 1: stats only, acc stays live across grid.sync
#pragma unroll
  for (int mi = 0; mi < 4; ++mi)
#pragma unroll
    for (int ni = 0; ni < 4; ++ni) acc[mi][ni] = int32x4{0, 0, 0, 0};
  gemm_tile(Abin, Bbin, row1, col1, K, sA, sB, wave, lane, acc);
  tile_stats(acc, colSum, colSq, C, N, row1, col1, wave, lane, false);

  grid.sync();  // all stats complete device-wide

  // ---- phase 2a: tile 1 normalized from registers ------------------------
  const float invM = 1.0f / (float)M;
  {
    const int f    = lane & 15;
    const int quad = lane >> 4;
    const int wr = (wave >> 1) * 64;
    const int wc = (wave & 1) * 64;
#pragma unroll
    for (int ni = 0; ni < 4; ++ni) {
      const int col = col1 + wc + ni * 16 + f;
      const float mean = colSum[col] * invM;
      const float var  = colSq[col] * invM - mean * mean;  // biased
      const float sc   = gamma[col] * rsqrtf(var + EPS_BN);
      const float sh   = beta[col] - mean * sc;
#pragma unroll
      for (int mi = 0; mi < 4; ++mi) {
        const int r0 = row1 + wr + mi * 16 + quad * 4;
        float* Cp = C + (size_t)r0 * N + col;
#pragma unroll
        for (int r = 0; r < 4; ++r)
          Cp[(size_t)r * N] = (float)acc[mi][ni][r] * sc + sh;
      }
    }
  }

  // ---- phase 2b: tile 0 re-read + normalize (coalesced float4) -----------
  {
    const int c4  = tid & 31;  // 32 float4 per 128-col row
    const int r0  = tid >> 5;  // 8 row-lanes
    const int col = col0 + c4 * 4;
    const float4 sm = *reinterpret_cast<const float4*>(&colSum[col]);
    const float4 sv = *reinterpret_cast<const float4*>(&colSq[col]);
    const float4 g  = *reinterpret_cast<const float4*>(&gamma[col]);
    const float4 b  = *reinterpret_cast<const float4*>(&beta[col]);
    float4 sc, sh;
    {
      float m, vv;
      m = sm.x * invM; vv = sv.x * invM - m * m;
      sc.x = g.x * rsqrtf(vv + EPS_BN); sh.x = b.x - m * sc.x;
      m = sm.y * invM; vv = sv.y * invM - m * m;
      sc.y = g.y * rsqrtf(vv + EPS_BN); sh.y = b.y - m * sc.y;
      m = sm.z * invM; vv = sv.z * invM - m * m;
      sc.z = g.z * rsqrtf(vv + EPS_BN); sh.z = b.z - m * sc.z;
      m = sm.w * invM; vv = sv.w * invM - m * m;
      sc.w = g.w * rsqrtf(vv + EPS_BN); sh.w = b.w - m * sc.w;
    }
    for (int r = r0; r < BM; r += 8) {
      float4* p = reinterpret_cast<float4*>(C + (size_t)(row0 + r) * N + col);
      float4 v = *p;
      v.x = v.x * sc.x + sh.x;
      v.y = v.y * sc.y + sh.y;
      v.z = v.z * sc.z + sh.z;
      v.w = v.w * sc.w + sh.w;
      *p = v;
    }
  }
}

// ---- fallback pipeline (used only if cooperative launch fails) ------------
__global__ void binarize_kernel(const float* __restrict__ x,
                                const float* __restrict__ w,
                                char* __restrict__ Ab, char* __restrict__ Bb,
                                int nx4, int ntot4) {
  int idx = blockIdx.x * blockDim.x + threadIdx.x;
  if (idx >= ntot4) return;
  const float4* src;
  char* dst;
  int i;
  if (idx < nx4) {
    src = reinterpret_cast<const float4*>(x); dst = Ab; i = idx;
  } else {
    src = reinterpret_cast<const float4*>(w); dst = Bb; i = idx - nx4;
  }
  float4 v = src[i];
  char4 o;
  o.x = sgn(v.x); o.y = sgn(v.y); o.z = sgn(v.z); o.w = sgn(v.w);
  reinterpret_cast<char4*>(dst)[i] = o;
}

__global__ __launch_bounds__(256) void gemm_i8_kernel(
    const char* __restrict__ A, const char* __restrict__ Bt,
    float* __restrict__ C, float* __restrict__ colSum,
    float* __restrict__ colSq, int M, int N, int K) {
  __shared__ __align__(16) char sA[BM * BKI];
  __shared__ __align__(16) char sB[BN * BKI];
  const int tid = threadIdx.x;
  const int wave = tid >> 6, lane = tid & 63;
  const int nby = M / BM;
  const int rowBlock = (blockIdx.x % nby) * BM;
  const int colBlock = (blockIdx.x / nby) * BN;
  int32x4 acc[4][4];
#pragma unroll
  for (int mi = 0; mi < 4; ++mi)
#pragma unroll
    for (int ni = 0; ni < 4; ++ni) acc[mi][ni] = int32x4{0, 0, 0, 0};
  gemm_tile(A, Bt, rowBlock, colBlock, K, sA, sB, wave, lane, acc);
  tile_stats(acc, colSum, colSq, C, N, rowBlock, colBlock, wave, lane, true);
}

__global__ void norm_fused_kernel(float* __restrict__ C,
                                  const float* __restrict__ colSum,
                                  const float* __restrict__ colSq,
                                  const float* __restrict__ gamma,
                                  const float* __restrict__ beta, int ncol4,
                                  float invM) {
  int c4 = blockIdx.x * blockDim.x + threadIdx.x;
  if (c4 >= ncol4) return;
  size_t row = blockIdx.y;
  int col = c4 * 4;
  const float4 sm = *reinterpret_cast<const float4*>(&colSum[col]);
  const float4 sv = *reinterpret_cast<const float4*>(&colSq[col]);
  const float4 g  = *reinterpret_cast<const float4*>(&gamma[col]);
  const float4 b  = *reinterpret_cast<const float4*>(&beta[col]);
  float4 v = reinterpret_cast<float4*>(C)[row * ncol4 + c4];
  float m, vv, sc;
  m = sm.x * invM; vv = sv.x * invM - m * m;
  sc = g.x * rsqrtf(vv + EPS_BN); v.x = v.x * sc + b.x - m * sc;
  m = sm.y * invM; vv = sv.y * invM - m * m;
  sc = g.y * rsqrtf(vv + EPS_BN); v.y = v.y * sc + b.y - m * sc;
  m = sm.z * invM; vv = sv.z * invM - m * m;
  sc = g.z * rsqrtf(vv + EPS_BN); v.z = v.z * sc + b.z - m * sc;
  m = sm.w * invM; vv = sv.w * invM - m * m;
  sc = g.w * rsqrtf(vv + EPS_BN); v.w = v.w * sc + b.w - m * sc;
  reinterpret_cast<float4*>(C)[row * ncol4 + c4] = v;
}

// ---------------------------------------------------------------------------
extern "C" void kernel_launch(void* const* d_in, const int* in_sizes, int n_in,
                              void* d_out, int out_size, void* d_ws,
                              size_t ws_size, hipStream_t stream) {
  const float* x     = (const float*)d_in[0];
  const float* w     = (const float*)d_in[1];
  const float* gamma = (const float*)d_in[2];
  const float* beta  = (const float*)d_in[3];
  float* C = (float*)d_out;

  int N = in_sizes[2];      // OUT
  int K = in_sizes[1] / N;  // IN
  int M = in_sizes[0] / K;  // batch

  // workspace: [A i8 M*K][B i8 N*K][colSum N][colSq N]
  char* ws = (char*)d_ws;
  char* Abin = ws;
  char* Bbin = ws + (size_t)M * K;
  float* stats = (float*)(ws + (size_t)M * K + (size_t)N * K);
  float* colSum = stats;
  float* colSq  = stats + N;

  const int nTiles = (M / BM) * (N / BN);  // 1024
  const int nBlocks = nTiles / 2;          // 512: fits 2-3 blk/CU budget

  void* args[] = {&x, &w, &gamma, &beta, &Abin, &Bbin,
                  &colSum, &colSq, &C, &M, &N, &K};
  hipError_t err = hipLaunchCooperativeKernel(
      (const void*)bnn_fused_kernel, dim3(nBlocks), dim3(256), args, 0, stream);

  if (err != hipSuccess) {
    // fallback: multi-kernel pipeline (round-2 style, fused normalize)
    (void)hipGetLastError();
    hipMemsetAsync(colSum, 0, 2 * (size_t)N * sizeof(float), stream);
    int nx4 = (M * K) / 4;
    int ntot4 = (M * K + N * K) / 4;
    binarize_kernel<<<(ntot4 + 255) / 256, 256, 0, stream>>>(x, w, Abin, Bbin,
                                                             nx4, ntot4);
    gemm_i8_kernel<<<nTiles, 256, 0, stream>>>(Abin, Bbin, C, colSum, colSq,
                                               M, N, K);
    dim3 ngrid((N / 4 + 255) / 256, M);
    norm_fused_kernel<<<ngrid, 256, 0, stream>>>(C, colSum, colSq, gamma, beta,
                                                 N / 4, 1.0f / (float)M);
  }
}

// Round 5
// 191.377 us; speedup vs baseline: 1.6359x; 1.6359x over previous
//
#include <hip/hip_runtime.h>
#include <stdint.h>

// ---------------------------------------------------------------------------
// BNNLinear: out = BatchNorm( sign(x) @ sign(W)^T )
//   x: [M, K] f32, W: [N, K] f32, gamma/beta: [N] f32  ->  out: [M, N] f32
//
// Round 5: back to multi-kernel (round-4's cooperative fusion lost 3x on the
// GEMM phase: same 13.5 us MFMA-busy, 204 us wall at 2 blk/CU; and the "aux"
// cost was mostly fixed harness overhead). Changes vs round 2:
//   - GEMM BK=128 (i8 -> only 32 KB LDS, keeps 3 blk/CU): half the barriers
//   - XOR-swizzled LDS staging: kills the 2 cyc/ds_read bank conflicts
//     (swizzle applied to the GLOBAL source addr; global_load_lds dest stays
//     linear as the DMA requires)
//   - raw C stored as int16 (|C| <= K=2048, exact): 32 MB instead of 64
//   - stats zeroing fused into binarize; finalize fused into normalize
// ---------------------------------------------------------------------------

typedef int int32x4 __attribute__((ext_vector_type(4)));

#define BM 128
#define BN 128
#define BKI 128  // i8 k-bytes per LDS tile
#define EPS_BN 1e-5f

__device__ __forceinline__ void load16_lds(const void* g, void* l) {
  // 16B per lane, LDS dest = wave-uniform base + lane*16 (linear, no scatter)
  __builtin_amdgcn_global_load_lds(
      (const __attribute__((address_space(1))) void*)g,
      (__attribute__((address_space(3))) void*)l,
      16, 0, 0);
}

__device__ __forceinline__ char sgn(float v) {
  return v > 0.f ? (char)1 : (v < 0.f ? (char)-1 : (char)0);
}

// ---- 1) binarize f32 -> i8 sign (both tensors) + zero stats ---------------
__global__ void binarize_kernel(const float* __restrict__ x,
                                const float* __restrict__ w,
                                char* __restrict__ Ab, char* __restrict__ Bb,
                                float* __restrict__ stats,  // colSum|colSq
                                int nx4, int ntot4, int n2) {
  int idx = blockIdx.x * blockDim.x + threadIdx.x;
  if (idx < n2) stats[idx] = 0.f;
  if (idx >= ntot4) return;
  const float4* src;
  char* dst;
  int i;
  if (idx < nx4) {
    src = reinterpret_cast<const float4*>(x); dst = Ab; i = idx;
  } else {
    src = reinterpret_cast<const float4*>(w); dst = Bb; i = idx - nx4;
  }
  float4 v = src[i];
  char4 o;
  o.x = sgn(v.x); o.y = sgn(v.y); o.z = sgn(v.z); o.w = sgn(v.w);
  reinterpret_cast<char4*>(dst)[i] = o;
}

// ---- 2) GEMM: C[i][j] = sum_k A[i][k]*Bt[j][k] (i8 -> i32 exact) ----------
// LDS swizzle: row r's 16B chunk c holds global k-chunk (c ^ (r&7)).
// Staging applies the XOR on the global address (dest stays linear);
// readers apply the same XOR. A quad's 8 distinct (f&7) values then span
// all 32 banks -> conflict-free ds_read_b128.
__global__ __launch_bounds__(256) void gemm_i8_kernel(
    const char* __restrict__ A,    // [M][K] i8
    const char* __restrict__ Bt,   // [N][K] i8
    short* __restrict__ Craw,      // [M][N] i16 (exact: |C| <= K)
    float* __restrict__ colSum,    // [N] (pre-zeroed)
    float* __restrict__ colSq,     // [N] (pre-zeroed)
    int M, int N, int K) {
  __shared__ __align__(16) char sA[BM * BKI];  // 16 KiB
  __shared__ __align__(16) char sB[BN * BKI];  // 16 KiB

  const int tid  = threadIdx.x;
  const int wave = tid >> 6;
  const int lane = tid & 63;

  // consecutive block-ids share the same B panel (L2 locality)
  const int nby = M / BM;
  const int rowBlock = (blockIdx.x % nby) * BM;
  const int colBlock = (blockIdx.x / nby) * BN;

  // staging: per wave 32 rows A + 32 rows B; one call = 64 lanes x 16B
  // = 8 rows x 128B. 4 calls each.
  const int laneRow = lane >> 3;                    // 0..7 (== row & 7)
  const int c       = lane & 7;                     // chunk slot 0..7
  const int swz     = ((c ^ laneRow) & 7) * 16;     // global k-byte offset

  const char* Ag = A  + (size_t)(rowBlock + wave * 32 + laneRow) * K + swz;
  const char* Bg = Bt + (size_t)(colBlock + wave * 32 + laneRow) * K + swz;
  char* sAw = &sA[(wave * 32) * BKI];
  char* sBw = &sB[(wave * 32) * BKI];

  const int f    = lane & 15;  // m (A) / n (B) index
  const int quad = lane >> 4;  // k-group selector
  const int wr = (wave >> 1) * 64;
  const int wc = (wave & 1) * 64;

  // reader chunk indices: global chunk g = s*4+quad -> LDS chunk g^(f&7)
  const int f7 = f & 7;

  int32x4 acc[4][4] = {};

  for (int k0 = 0; k0 < K; k0 += BKI) {
    __syncthreads();  // prior ds_reads complete before overwrite
#pragma unroll
    for (int i = 0; i < 4; ++i) {
      load16_lds(Ag + k0 + (size_t)(i * 8) * K, sAw + i * 8 * BKI);
      load16_lds(Bg + k0 + (size_t)(i * 8) * K, sBw + i * 8 * BKI);
    }
    __syncthreads();  // vmcnt drain -> staging visible

#pragma unroll
    for (int s = 0; s < 2; ++s) {  // two K=64 sub-steps
      const int chunk = ((s * 4 + quad) ^ f7) * 16;
      int32x4 af[4], bfr[4];
#pragma unroll
      for (int mi = 0; mi < 4; ++mi)
        af[mi] = *reinterpret_cast<const int32x4*>(
            &sA[(wr + mi * 16 + f) * BKI + chunk]);
#pragma unroll
      for (int ni = 0; ni < 4; ++ni)
        bfr[ni] = *reinterpret_cast<const int32x4*>(
            &sB[(wc + ni * 16 + f) * BKI + chunk]);
#pragma unroll
      for (int mi = 0; mi < 4; ++mi)
#pragma unroll
        for (int ni = 0; ni < 4; ++ni)
          acc[mi][ni] = __builtin_amdgcn_mfma_i32_16x16x64_i8(
              af[mi], bfr[ni], acc[mi][ni], 0, 0, 0);
    }
  }

  // epilogue: C/D layout col = lane&15, row = quad*4 + reg (verified).
  // Store raw C as int16 (exact); per-column sum/sumsq atomics (exact).
#pragma unroll
  for (int ni = 0; ni < 4; ++ni) {
    const int col = colBlock + wc + ni * 16 + f;
    float s = 0.f, sq = 0.f;
#pragma unroll
    for (int mi = 0; mi < 4; ++mi) {
      const int row0 = rowBlock + wr + mi * 16 + quad * 4;
      short* Cp = Craw + (size_t)row0 * N + col;
#pragma unroll
      for (int r = 0; r < 4; ++r) {
        const int v = acc[mi][ni][r];
        Cp[(size_t)r * N] = (short)v;
        const float fv = (float)v;
        s += fv;
        sq += fv * fv;
      }
    }
    s  += __shfl_xor(s, 16);  s  += __shfl_xor(s, 32);
    sq += __shfl_xor(sq, 16); sq += __shfl_xor(sq, 32);
    if (quad == 0) {
      atomicAdd(&colSum[col], s);
      atomicAdd(&colSq[col], sq);
    }
  }
}

// ---- 3) finalize + normalize: C = raw*scale + shift -----------------------
__global__ void norm_kernel(const short* __restrict__ Craw,
                            float* __restrict__ C,
                            const float* __restrict__ colSum,
                            const float* __restrict__ colSq,
                            const float* __restrict__ gamma,
                            const float* __restrict__ beta,
                            int ncol4mask, int ncol4shift, float invM) {
  const int idx = blockIdx.x * blockDim.x + threadIdx.x;
  const int c4  = idx & ncol4mask;        // N/4 is a power of two
  const size_t row = (size_t)(idx >> ncol4shift);
  const int col = c4 * 4;

  const float4 sm = *reinterpret_cast<const float4*>(&colSum[col]);
  const float4 sv = *reinterpret_cast<const float4*>(&colSq[col]);
  const float4 g  = *reinterpret_cast<const float4*>(&gamma[col]);
  const float4 b  = *reinterpret_cast<const float4*>(&beta[col]);

  const short4 rv = reinterpret_cast<const short4*>(Craw)[idx];

  float4 o;
  float m, vv, sc;
  m = sm.x * invM; vv = sv.x * invM - m * m;
  sc = g.x * rsqrtf(vv + EPS_BN); o.x = (float)rv.x * sc + (b.x - m * sc);
  m = sm.y * invM; vv = sv.y * invM - m * m;
  sc = g.y * rsqrtf(vv + EPS_BN); o.y = (float)rv.y * sc + (b.y - m * sc);
  m = sm.z * invM; vv = sv.z * invM - m * m;
  sc = g.z * rsqrtf(vv + EPS_BN); o.z = (float)rv.z * sc + (b.z - m * sc);
  m = sm.w * invM; vv = sv.w * invM - m * m;
  sc = g.w * rsqrtf(vv + EPS_BN); o.w = (float)rv.w * sc + (b.w - m * sc);

  reinterpret_cast<float4*>(C)[idx] = o;
}

// ---------------------------------------------------------------------------
extern "C" void kernel_launch(void* const* d_in, const int* in_sizes, int n_in,
                              void* d_out, int out_size, void* d_ws,
                              size_t ws_size, hipStream_t stream) {
  const float* x     = (const float*)d_in[0];
  const float* w     = (const float*)d_in[1];
  const float* gamma = (const float*)d_in[2];
  const float* beta  = (const float*)d_in[3];
  float* C = (float*)d_out;

  const int N = in_sizes[2];      // OUT
  const int K = in_sizes[1] / N;  // IN
  const int M = in_sizes[0] / K;  // batch

  // workspace: [A i8 M*K][B i8 N*K][Craw i16 M*N][colSum N][colSq N]
  char* ws = (char*)d_ws;
  char* Abin = ws;
  char* Bbin = ws + (size_t)M * K;
  short* Craw = (short*)(ws + (size_t)M * K + (size_t)N * K);
  float* stats = (float*)((char*)Craw + (size_t)M * N * sizeof(short));
  float* colSum = stats;
  float* colSq  = stats + N;

  {
    int nx4 = (M * K) / 4;
    int ntot4 = (M * K + N * K) / 4;
    binarize_kernel<<<(ntot4 + 255) / 256, 256, 0, stream>>>(
        x, w, Abin, Bbin, stats, nx4, ntot4, 2 * N);
  }

  const int nTiles = (M / BM) * (N / BN);  // 1024
  gemm_i8_kernel<<<nTiles, 256, 0, stream>>>(Abin, Bbin, Craw, colSum, colSq,
                                             M, N, K);

  {
    // N/4 is a power of two (N=2048 -> 512): index split via mask/shift
    int ncol4 = N / 4;
    int shift = 0;
    while ((1 << shift) < ncol4) ++shift;
    int total = (M * N) / 4;
    norm_kernel<<<(total + 255) / 256, 256, 0, stream>>>(
        Craw, C, colSum, colSq, gamma, beta, ncol4 - 1, shift,
        1.0f / (float)M);
  }
}

// Round 6
// 179.524 us; speedup vs baseline: 1.7439x; 1.0660x over previous
//
#include <hip/hip_runtime.h>
#include <stdint.h>

// ---------------------------------------------------------------------------
// BNNLinear: out = BatchNorm( sign(x) @ sign(W)^T )
//   x: [M, K] f32, W: [N, K] f32, gamma/beta: [N] f32  ->  out: [M, N] f32
//
// Round 6 (on round 5: BK=128 i8 GEMM, XOR-swizzled LDS -> 0 bank conflicts,
// i16 raw C):
//   - gemm __launch_bounds__(256, 4): cap combined VGPR+AGPR at 128 ->
//     4 blocks/CU, grid 1024 = 256 CUs x 4 exactly (no residency tail).
//     R5 was 152 regs -> 3/CU -> 768+256 tail with exposed latency.
//   - norm: 2 rows per thread (stats reuse, half the grid)
// ---------------------------------------------------------------------------

typedef int int32x4 __attribute__((ext_vector_type(4)));

#define BM 128
#define BN 128
#define BKI 128  // i8 k-bytes per LDS tile
#define EPS_BN 1e-5f

__device__ __forceinline__ void load16_lds(const void* g, void* l) {
  // 16B per lane, LDS dest = wave-uniform base + lane*16 (linear, no scatter)
  __builtin_amdgcn_global_load_lds(
      (const __attribute__((address_space(1))) void*)g,
      (__attribute__((address_space(3))) void*)l,
      16, 0, 0);
}

__device__ __forceinline__ char sgn(float v) {
  return v > 0.f ? (char)1 : (v < 0.f ? (char)-1 : (char)0);
}

// ---- 1) binarize f32 -> i8 sign (both tensors) + zero stats ---------------
__global__ void binarize_kernel(const float* __restrict__ x,
                                const float* __restrict__ w,
                                char* __restrict__ Ab, char* __restrict__ Bb,
                                float* __restrict__ stats,  // colSum|colSq
                                int nx4, int ntot4, int n2) {
  int idx = blockIdx.x * blockDim.x + threadIdx.x;
  if (idx < n2) stats[idx] = 0.f;
  if (idx >= ntot4) return;
  const float4* src;
  char* dst;
  int i;
  if (idx < nx4) {
    src = reinterpret_cast<const float4*>(x); dst = Ab; i = idx;
  } else {
    src = reinterpret_cast<const float4*>(w); dst = Bb; i = idx - nx4;
  }
  float4 v = src[i];
  char4 o;
  o.x = sgn(v.x); o.y = sgn(v.y); o.z = sgn(v.z); o.w = sgn(v.w);
  reinterpret_cast<char4*>(dst)[i] = o;
}

// ---- 2) GEMM: C[i][j] = sum_k A[i][k]*Bt[j][k] (i8 -> i32 exact) ----------
// LDS swizzle: row r's 16B chunk c holds global k-chunk (c ^ (r&7)); staging
// applies the XOR on the global address (DMA dest stays linear); readers
// apply the same XOR. Measured round 5: SQ_LDS_BANK_CONFLICT == 0.
__global__ __launch_bounds__(256, 4) void gemm_i8_kernel(
    const char* __restrict__ A,    // [M][K] i8
    const char* __restrict__ Bt,   // [N][K] i8
    short* __restrict__ Craw,      // [M][N] i16 (exact: |C| <= K)
    float* __restrict__ colSum,    // [N] (pre-zeroed)
    float* __restrict__ colSq,     // [N] (pre-zeroed)
    int M, int N, int K) {
  __shared__ __align__(16) char sA[BM * BKI];  // 16 KiB
  __shared__ __align__(16) char sB[BN * BKI];  // 16 KiB

  const int tid  = threadIdx.x;
  const int wave = tid >> 6;
  const int lane = tid & 63;

  // consecutive block-ids share the same B panel (L2 locality)
  const int nby = M / BM;
  const int rowBlock = (blockIdx.x % nby) * BM;
  const int colBlock = (blockIdx.x / nby) * BN;

  // staging: per wave 32 rows A + 32 rows B; one call = 64 lanes x 16B
  // = 8 rows x 128B. 4 calls each.
  const int laneRow = lane >> 3;                 // 0..7 (== row & 7)
  const int c       = lane & 7;                  // chunk slot 0..7
  const int swz     = ((c ^ laneRow) & 7) * 16;  // global k-byte offset

  const char* Ag = A  + (size_t)(rowBlock + wave * 32 + laneRow) * K + swz;
  const char* Bg = Bt + (size_t)(colBlock + wave * 32 + laneRow) * K + swz;
  char* sAw = &sA[(wave * 32) * BKI];
  char* sBw = &sB[(wave * 32) * BKI];

  const int f    = lane & 15;  // m (A) / n (B) index
  const int quad = lane >> 4;  // k-group selector
  const int wr = (wave >> 1) * 64;
  const int wc = (wave & 1) * 64;
  const int f7 = f & 7;

  int32x4 acc[4][4] = {};

  for (int k0 = 0; k0 < K; k0 += BKI) {
    __syncthreads();  // prior ds_reads complete before overwrite
#pragma unroll
    for (int i = 0; i < 4; ++i) {
      load16_lds(Ag + k0 + (size_t)(i * 8) * K, sAw + i * 8 * BKI);
      load16_lds(Bg + k0 + (size_t)(i * 8) * K, sBw + i * 8 * BKI);
    }
    __syncthreads();  // vmcnt drain -> staging visible

#pragma unroll
    for (int s = 0; s < 2; ++s) {  // two K=64 sub-steps
      const int chunk = ((s * 4 + quad) ^ f7) * 16;
      int32x4 af[4], bfr[4];
#pragma unroll
      for (int mi = 0; mi < 4; ++mi)
        af[mi] = *reinterpret_cast<const int32x4*>(
            &sA[(wr + mi * 16 + f) * BKI + chunk]);
#pragma unroll
      for (int ni = 0; ni < 4; ++ni)
        bfr[ni] = *reinterpret_cast<const int32x4*>(
            &sB[(wc + ni * 16 + f) * BKI + chunk]);
#pragma unroll
      for (int mi = 0; mi < 4; ++mi)
#pragma unroll
        for (int ni = 0; ni < 4; ++ni)
          acc[mi][ni] = __builtin_amdgcn_mfma_i32_16x16x64_i8(
              af[mi], bfr[ni], acc[mi][ni], 0, 0, 0);
    }
  }

  // epilogue: C/D layout col = lane&15, row = quad*4 + reg (verified).
  // Store raw C as int16 (exact); per-column sum/sumsq atomics (exact).
#pragma unroll
  for (int ni = 0; ni < 4; ++ni) {
    const int col = colBlock + wc + ni * 16 + f;
    float s = 0.f, sq = 0.f;
#pragma unroll
    for (int mi = 0; mi < 4; ++mi) {
      short* Cp = Craw + (size_t)(rowBlock + wr + mi * 16 + quad * 4) * N + col;
#pragma unroll
      for (int r = 0; r < 4; ++r) {
        const int v = acc[mi][ni][r];
        Cp[(size_t)r * N] = (short)v;
        const float fv = (float)v;
        s += fv;
        sq += fv * fv;
      }
    }
    s  += __shfl_xor(s, 16);  s  += __shfl_xor(s, 32);
    sq += __shfl_xor(sq, 16); sq += __shfl_xor(sq, 32);
    if (quad == 0) {
      atomicAdd(&colSum[col], s);
      atomicAdd(&colSq[col], sq);
    }
  }
}

// ---- 3) finalize + normalize: C = raw*scale + shift (2 rows/thread) -------
__global__ void norm_kernel(const short* __restrict__ Craw,
                            float* __restrict__ C,
                            const float* __restrict__ colSum,
                            const float* __restrict__ colSq,
                            const float* __restrict__ gamma,
                            const float* __restrict__ beta,
                            int ncol4mask, int ncol4shift, int halfRows,
                            float invM) {
  const int idx = blockIdx.x * blockDim.x + threadIdx.x;
  const int c4  = idx & ncol4mask;  // N/4 is a power of two
  const int row = idx >> ncol4shift;
  const int col = c4 * 4;
  const int ncol4 = ncol4mask + 1;

  const float4 sm = *reinterpret_cast<const float4*>(&colSum[col]);
  const float4 sv = *reinterpret_cast<const float4*>(&colSq[col]);
  const float4 g  = *reinterpret_cast<const float4*>(&gamma[col]);
  const float4 b  = *reinterpret_cast<const float4*>(&beta[col]);

  float4 sc, sh;
  {
    float m, vv;
    m = sm.x * invM; vv = sv.x * invM - m * m;
    sc.x = g.x * rsqrtf(vv + EPS_BN); sh.x = b.x - m * sc.x;
    m = sm.y * invM; vv = sv.y * invM - m * m;
    sc.y = g.y * rsqrtf(vv + EPS_BN); sh.y = b.y - m * sc.y;
    m = sm.z * invM; vv = sv.z * invM - m * m;
    sc.z = g.z * rsqrtf(vv + EPS_BN); sh.z = b.z - m * sc.z;
    m = sm.w * invM; vv = sv.w * invM - m * m;
    sc.w = g.w * rsqrtf(vv + EPS_BN); sh.w = b.w - m * sc.w;
  }

#pragma unroll
  for (int h = 0; h < 2; ++h) {
    const size_t e = (size_t)(row + h * halfRows) * ncol4 + c4;
    const short4 rv = reinterpret_cast<const short4*>(Craw)[e];
    float4 o;
    o.x = (float)rv.x * sc.x + sh.x;
    o.y = (float)rv.y * sc.y + sh.y;
    o.z = (float)rv.z * sc.z + sh.z;
    o.w = (float)rv.w * sc.w + sh.w;
    reinterpret_cast<float4*>(C)[e] = o;
  }
}

// ---------------------------------------------------------------------------
extern "C" void kernel_launch(void* const* d_in, const int* in_sizes, int n_in,
                              void* d_out, int out_size, void* d_ws,
                              size_t ws_size, hipStream_t stream) {
  const float* x     = (const float*)d_in[0];
  const float* w     = (const float*)d_in[1];
  const float* gamma = (const float*)d_in[2];
  const float* beta  = (const float*)d_in[3];
  float* C = (float*)d_out;

  const int N = in_sizes[2];      // OUT
  const int K = in_sizes[1] / N;  // IN
  const int M = in_sizes[0] / K;  // batch

  // workspace: [A i8 M*K][B i8 N*K][Craw i16 M*N][colSum N][colSq N]
  char* ws = (char*)d_ws;
  char* Abin = ws;
  char* Bbin = ws + (size_t)M * K;
  short* Craw = (short*)(ws + (size_t)M * K + (size_t)N * K);
  float* stats = (float*)((char*)Craw + (size_t)M * N * sizeof(short));
  float* colSum = stats;
  float* colSq  = stats + N;

  {
    int nx4 = (M * K) / 4;
    int ntot4 = (M * K + N * K) / 4;
    binarize_kernel<<<(ntot4 + 255) / 256, 256, 0, stream>>>(
        x, w, Abin, Bbin, stats, nx4, ntot4, 2 * N);
  }

  const int nTiles = (M / BM) * (N / BN);  // 1024 = 256 CUs x 4 blocks
  gemm_i8_kernel<<<nTiles, 256, 0, stream>>>(Abin, Bbin, Craw, colSum, colSq,
                                             M, N, K);

  {
    int ncol4 = N / 4;  // power of two (512)
    int shift = 0;
    while ((1 << shift) < ncol4) ++shift;
    int total = (M / 2) * ncol4;  // 2 rows per thread
    norm_kernel<<<(total + 255) / 256, 256, 0, stream>>>(
        Craw, C, colSum, colSq, gamma, beta, ncol4 - 1, shift, M / 2,
        1.0f / (float)M);
  }
}